// Round 12
// baseline (170.180 us; speedup 1.0000x reference)
//
#include <hip/hip_runtime.h>
#include <hip/hip_bf16.h>

// Problem constants (hardcoded from setup_inputs; n_shifts == T == 64)
#define NB   4096
#define NT   64
#define NDIM 16
#define NH1  256
#define NH2  256
#define NLAT 64
#define NKD  80
#define YROW (NT * NKD)      // 5120 floats per batch row of y / y_pred
#define KTAB 98304           // short-offset of K-power fragment table in ws
#define KSLOT 15360          // shorts per t-slot (7680 hi + 7680 lo)
#define Y0F   1081344        // short-offset of y0 A-frag table
#define HPLANE 393216        // shorts per plane: 256 mtiles x 3 kk x 64 lane x 8 e

// kpow frag-image geometry: hi at [row][0..79], lo at [row][96..175]
#define FROW 184
#define FIMG_B (80 * FROW * 2)   // 29440 bytes per image

typedef __attribute__((ext_vector_type(8))) short bf16x8;
typedef __attribute__((ext_vector_type(4))) float f32x4;

#define MFMA __builtin_amdgcn_mfma_f32_16x16x32_bf16

static __device__ __forceinline__ short f2bf(float f) {
  __hip_bfloat16 b = __float2bfloat16(f);
  return __builtin_bit_cast(short, b);
}
static __device__ __forceinline__ float bf2f(short h) {
  union { unsigned u; float f; } v; v.u = ((unsigned)(unsigned short)h) << 16;
  return v.f;
}
static __device__ __forceinline__ bf16x8 pack8(float4 a, float4 b) {
  bf16x8 r;
  r[0] = f2bf(a.x); r[1] = f2bf(a.y); r[2] = f2bf(a.z); r[3] = f2bf(a.w);
  r[4] = f2bf(b.x); r[5] = f2bf(b.y); r[6] = f2bf(b.z); r[7] = f2bf(b.w);
  return r;
}

// ---------------------------------------------------------------------------
// Prep: MFMA fragment order (bf16) for 16x16x32.
// Fragment: lane l holds W[g][k] with g = l&15, k = 8*(l>>4)+e.
// ws (shorts): [0) W2f 65536 | [65536) W3f 16384 | [81920) W1f 8192
// ---------------------------------------------------------------------------
__global__ __launch_bounds__(256) void prep_kernel(const float* __restrict__ W1,
                                                   const float* __restrict__ W2,
                                                   const float* __restrict__ W3,
                                                   short* __restrict__ ws) {
  int i = blockIdx.x * 256 + threadIdx.x;   // 0..65535
  {
    int e = i & 7, l = (i >> 3) & 63, nt = (i >> 9) & 15, kk = i >> 13;
    int g = nt * 16 + (l & 15);
    int h = kk * 32 + (l >> 4) * 8 + e;
    ws[i] = f2bf(W2[g * NH1 + h]);
  }
  if (i < 16384) {
    int e = i & 7, l = (i >> 3) & 63, nt = (i >> 9) & 3, kk = i >> 11;
    int g = nt * 16 + (l & 15);
    int h = kk * 32 + (l >> 4) * 8 + e;
    ws[65536 + i] = f2bf(W3[g * NH2 + h]);
  }
  if (i < 8192) {
    int e = i & 7, l = (i >> 3) & 63, nt = i >> 9;
    int g = nt * 16 + (l & 15);
    int k = (l >> 4) * 8 + e;
    ws[81920 + i] = (k < NDIM) ? f2bf(W1[g * NDIM + k]) : (short)0;
  }
}

// ---------------------------------------------------------------------------
// mlp0 body (round-8 64-token shape, MODE-1 epilogue only): token-0 MLP,
// emits the y0 hi/lo A-fragment table at ws[Y0F].
// ---------------------------------------------------------------------------
static __device__ __forceinline__ void mlp0_body(long b, const float* __restrict__ x,
                                                 const float* __restrict__ b1g,
                                                 const float* __restrict__ b2g,
                                                 const short* __restrict__ ws,
                                                 short* __restrict__ y0f,
                                                 short* h1s, int tid) {
  const int lane = tid & 63;
  const int w    = tid >> 6;            // 0..3
  const int l15  = lane & 15;
  const int kg   = lane >> 4;

  const short* W2f = ws;
  const short* W3f = ws + 65536;
  const short* W1f = ws + 81920;

  const float4 xv =
      *(const float4*)(x + (b * 64 + (tid >> 2)) * 1024 + (tid & 3) * 4);

  bf16x8 xf[4];
#pragma unroll
  for (int j = 0; j < 4; ++j) {
    const int tok = j * 16 + l15;
    bf16x8 f = {};
    if (kg < 2) {
      const float4* p = (const float4*)(x + (b * 64 + tok) * 1024 + kg * 8);
      f = pack8(p[0], p[1]);
    }
    xf[j] = f;
  }

#pragma unroll
  for (int i = 0; i < 4; ++i) {
    const int mt = w * 4 + i;
    const bf16x8 wa = *(const bf16x8*)(W1f + (mt * 64 + lane) * 8);
    const float4 bias = *(const float4*)(b1g + mt * 16 + kg * 4);
#pragma unroll
    for (int j = 0; j < 4; ++j) {
      f32x4 c = {0.f, 0.f, 0.f, 0.f};
      c = MFMA(wa, xf[j], c, 0, 0, 0);
      const int tok = j * 16 + l15;
      float v0 = c[0] + bias.x; v0 = v0 > 0.f ? v0 : 0.f;
      float v1 = c[1] + bias.y; v1 = v1 > 0.f ? v1 : 0.f;
      float v2 = c[2] + bias.z; v2 = v2 > 0.f ? v2 : 0.f;
      float v3 = c[3] + bias.w; v3 = v3 > 0.f ? v3 : 0.f;
      short4 st = {f2bf(v0), f2bf(v1), f2bf(v2), f2bf(v3)};
      *(short4*)(h1s + tok * 264 + mt * 16 + kg * 4) = st;
    }
  }
  __syncthreads();

  f32x4 acc2[4][4];
#pragma unroll
  for (int i = 0; i < 4; ++i)
#pragma unroll
    for (int j = 0; j < 4; ++j) acc2[i][j] = (f32x4){0.f, 0.f, 0.f, 0.f};

#pragma unroll 2
  for (int kk = 0; kk < 8; ++kk) {
    bf16x8 wa[4], hb[4];
#pragma unroll
    for (int i = 0; i < 4; ++i)
      wa[i] = *(const bf16x8*)(W2f + ((kk * 16 + w * 4 + i) * 64 + lane) * 8);
#pragma unroll
    for (int j = 0; j < 4; ++j)
      hb[j] = *(const bf16x8*)(h1s + (j * 16 + l15) * 264 + kk * 32 + kg * 8);
#pragma unroll
    for (int i = 0; i < 4; ++i)
#pragma unroll
      for (int j = 0; j < 4; ++j)
        acc2[i][j] = MFMA(wa[i], hb[j], acc2[i][j], 0, 0, 0);
  }
  __syncthreads();

#pragma unroll
  for (int i = 0; i < 4; ++i) {
    const int mt = w * 4 + i;
    const float4 bias = *(const float4*)(b2g + mt * 16 + kg * 4);
#pragma unroll
    for (int j = 0; j < 4; ++j) {
      const int tok = j * 16 + l15;
      float v0 = acc2[i][j][0] + bias.x; v0 = v0 > 0.f ? v0 : 0.f;
      float v1 = acc2[i][j][1] + bias.y; v1 = v1 > 0.f ? v1 : 0.f;
      float v2 = acc2[i][j][2] + bias.z; v2 = v2 > 0.f ? v2 : 0.f;
      float v3 = acc2[i][j][3] + bias.w; v3 = v3 > 0.f ? v3 : 0.f;
      short4 st = {f2bf(v0), f2bf(v1), f2bf(v2), f2bf(v3)};
      *(short4*)(h1s + tok * 264 + mt * 16 + kg * 4) = st;
    }
  }
  __syncthreads();

  f32x4 acc3[4];
#pragma unroll
  for (int j = 0; j < 4; ++j) acc3[j] = (f32x4){0.f, 0.f, 0.f, 0.f};
#pragma unroll 2
  for (int kk = 0; kk < 8; ++kk) {
    const bf16x8 wa = *(const bf16x8*)(W3f + ((kk * 4 + w) * 64 + lane) * 8);
#pragma unroll
    for (int j = 0; j < 4; ++j) {
      const bf16x8 hb =
          *(const bf16x8*)(h1s + (j * 16 + l15) * 264 + kk * 32 + kg * 8);
      acc3[j] = MFMA(wa, hb, acc3[j], 0, 0, 0);
    }
  }

  // ---- y0 hi/lo A-frag table epilogue ----
  {
    const int t0 = tid >> 2;
    const int gmt = (int)b * 4 + (t0 >> 4);
    const int c0x = (tid & 3) * 4;
    const int lanef = (c0x >> 3) * 16 + (t0 & 15);
    short h0 = f2bf(xv.x), h1 = f2bf(xv.y), h2 = f2bf(xv.z), h3 = f2bf(xv.w);
    short4 hs = {h0, h1, h2, h3};
    short4 ls = {f2bf(xv.x - bf2f(h0)), f2bf(xv.y - bf2f(h1)),
                 f2bf(xv.z - bf2f(h2)), f2bf(xv.w - bf2f(h3))};
    const int idx = ((gmt * 3 + 0) * 64 + lanef) * 8 + (c0x & 7);
    *(short4*)(y0f + idx) = hs;
    *(short4*)(y0f + HPLANE + idx) = ls;
  }
  const int c0 = 16 + w * 16 + kg * 4;
  const int kkf = c0 >> 5;
  const int lanef = ((c0 & 31) >> 3) * 16 + l15;
#pragma unroll
  for (int j = 0; j < 4; ++j) {
    const int gmt = (int)b * 4 + j;
    short h0 = f2bf(acc3[j][0]), h1 = f2bf(acc3[j][1]);
    short h2 = f2bf(acc3[j][2]), h3 = f2bf(acc3[j][3]);
    short4 hs = {h0, h1, h2, h3};
    short4 ls = {f2bf(acc3[j][0] - bf2f(h0)), f2bf(acc3[j][1] - bf2f(h1)),
                 f2bf(acc3[j][2] - bf2f(h2)), f2bf(acc3[j][3] - bf2f(h3))};
    const int idx = ((gmt * 3 + kkf) * 64 + lanef) * 8 + (c0 & 7);
    *(short4*)(y0f + idx) = hs;
    *(short4*)(y0f + HPLANE + idx) = ls;
  }
  {
    const int plane = tid & 1;
    const int lz = 32 + ((tid >> 1) & 31);
    const int gmt = (int)b * 4 + (tid >> 6);
    bf16x8 z = {};
    *(bf16x8*)(y0f + plane * HPLANE + ((gmt * 3 + 2) * 64 + lz) * 8) = z;
  }
}

// ---------------------------------------------------------------------------
// kpow+mlp0 fused launch (127 blocks, 256 thr): bid 0..62 kpow, 63..126 mlp0.
// ---------------------------------------------------------------------------
__global__ __launch_bounds__(256, 4) void kpow_mlp0_kernel(const float* __restrict__ Kg,
                                                           const float* __restrict__ x,
                                                           const float* __restrict__ b1g,
                                                           const float* __restrict__ b2g,
                                                           short* __restrict__ ws) {
  extern __shared__ char smem[];
  const int tid = threadIdx.x;

  if (blockIdx.x >= 63) {
    mlp0_body((long)(blockIdx.x - 63), x, b1g, b2g, ws, ws + Y0F, (short*)smem, tid);
    return;
  }

  short* kA   = (short*)smem;
  short* curA = (short*)(smem + FIMG_B);
  short* curB = (short*)(smem + 2 * FIMG_B);
  short* nxtA = (short*)(smem + 3 * FIMG_B);
  short* nxtB = (short*)(smem + 4 * FIMG_B);

  const int lane = tid & 63;
  const int w    = tid >> 6;            // 0..3
  const int l15  = lane & 15;
  const int kg   = lane >> 4;
  const int t    = blockIdx.x + 1;      // 1..63

  for (int i = tid; i < 6400; i += 256) {
    float v = Kg[i];
    int r = i / 80, c = i - r * 80;
    short hi = f2bf(v);
    short lo = f2bf(v - bf2f(hi));
    kA[r * FROW + c] = hi;        kA[r * FROW + 96 + c] = lo;
    curA[r * FROW + c] = hi;      curA[r * FROW + 96 + c] = lo;
    curB[c * FROW + r] = hi;      curB[c * FROW + 96 + r] = lo;
  }
  __syncthreads();

  auto mm = [&](const short* Ai, const short* Bi, short* DA, short* DB) {
    for (int id = w; id < 25; id += 4) {
      const int mt = id / 5, nt = id % 5;
      f32x4 acc = {0.f, 0.f, 0.f, 0.f};
#pragma unroll
      for (int kk = 0; kk < 3; ++kk) {
        const int k0 = kk * 32 + kg * 8;
        bf16x8 ah = {}, al = {}, bh = {}, bl = {};
        if (k0 < 80) {
          const short* ap = Ai + (mt * 16 + l15) * FROW + k0;
          const short* bp = Bi + (nt * 16 + l15) * FROW + k0;
          ah = *(const bf16x8*)ap;  al = *(const bf16x8*)(ap + 96);
          bh = *(const bf16x8*)bp;  bl = *(const bf16x8*)(bp + 96);
        }
        acc = MFMA(ah, bh, acc, 0, 0, 0);
        acc = MFMA(al, bh, acc, 0, 0, 0);
        acc = MFMA(ah, bl, acc, 0, 0, 0);
      }
      const int n = nt * 16 + l15;
      const int rowb = mt * 16 + kg * 4;
      short4 hs, ls;
#pragma unroll
      for (int r = 0; r < 4; ++r) {
        float v = acc[r];
        short hi = f2bf(v);
        short lo = f2bf(v - bf2f(hi));
        DA[(rowb + r) * FROW + n] = hi;
        DA[(rowb + r) * FROW + 96 + n] = lo;
        ((short*)&hs)[r] = hi;
        ((short*)&ls)[r] = lo;
      }
      *(short4*)(DB + n * FROW + rowb) = hs;
      *(short4*)(DB + n * FROW + 96 + rowb) = ls;
    }
    __syncthreads();
  };

  const int h = 31 - __clz(t);
  for (int bit = h - 1; bit >= 0; --bit) {
    mm(curA, curB, nxtA, nxtB);                               // square
    { short* p;
      p = curA; curA = nxtA; nxtA = p;
      p = curB; curB = nxtB; nxtB = p; }
    if ((t >> bit) & 1) {
      mm(kA, curB, nxtA, nxtB);                               // K * cur
      { short* p;
        p = curA; curA = nxtA; nxtA = p;
        p = curB; curB = nxtB; nxtB = p; }
    }
  }

  short* kt = ws + KTAB + t * KSLOT;
  for (int s = tid; s < 960; s += 256) {
    int f = s >> 6, ln = s & 63;            // f = kk*5 + nt
    int kk = f / 5, nt = f % 5;
    int k0 = kk * 32 + (ln >> 4) * 8;
    int n  = nt * 16 + (ln & 15);
    bf16x8 h8 = {}, l8 = {};
    if (k0 < 80) {
      const short* ap = curA + n * FROW + k0;
      h8 = *(const bf16x8*)ap;
      l8 = *(const bf16x8*)(ap + 96);
    }
    *(bf16x8*)(kt + f * 512 + ln * 8) = h8;
    *(bf16x8*)(kt + 7680 + f * 512 + ln * 8) = l8;
  }
}

// ---------------------------------------------------------------------------
// MLP v7: one block = FOUR batch rows (256 tokens), 512 threads = 8 waves,
// LDS h [256][264] bf16 = 135168 B -> 1 block/CU, 2 waves/SIMD (256 VGPR).
// GEMM2: wave owns 2 mt x 16 nt -> per K-step 32 MFMA (~620 cyc/SIMD)
// against 2 global + 16 LDS loads: latency fully buried, 4x the old
// MFMA:load ratio. W2 read once per 256 tokens (128 MB L2 total).
// GEMM1: wave -> mt {2w,2w+1} x 16 nt. GEMM3: mt3 = w&3, nt = (w>>2)*8+j.
// ---------------------------------------------------------------------------
__global__ __launch_bounds__(512, 2) void mlp256_kernel(const float* __restrict__ x,
                                                        const float* __restrict__ b1g,
                                                        const float* __restrict__ b2g,
                                                        const short* __restrict__ ws,
                                                        float* __restrict__ y) {
  extern __shared__ char smem[];
  short* h1s = (short*)smem;            // [256][264]; h2 overlays after barrier

  const int tid  = threadIdx.x;
  const int lane = tid & 63;
  const int w    = tid >> 6;            // 0..7
  const int l15  = lane & 15;
  const int kg   = lane >> 4;
  const long b   = blockIdx.x;          // 4 batch rows = 256 tokens

  const short* W2f = ws;
  const short* W3f = ws + 65536;
  const short* W1f = ws + 81920;

  // ---- y x-part early (exact f32 copy; frees registers) ----
#pragma unroll
  for (int i = 0; i < 2; ++i) {
    const int idx = i * 512 + tid;      // 0..1023
    const int tok = idx >> 2, c = (idx & 3) * 4;
    const float4 v = *(const float4*)(x + (b * 256 + tok) * 16 + c);
    *(float4*)(y + (b * 256 + tok) * 80 + c) = v;
  }

  // ---- GEMM1: h1 = relu(W1 x x^T + b1); wave -> mt {2w, 2w+1} ----
  {
    const bf16x8 wa0 = *(const bf16x8*)(W1f + ((2 * w) * 64 + lane) * 8);
    const bf16x8 wa1 = *(const bf16x8*)(W1f + ((2 * w + 1) * 64 + lane) * 8);
    const float4 bias0 = *(const float4*)(b1g + (2 * w) * 16 + kg * 4);
    const float4 bias1 = *(const float4*)(b1g + (2 * w + 1) * 16 + kg * 4);
#pragma unroll
    for (int nt = 0; nt < 16; ++nt) {
      const int tok = nt * 16 + l15;
      bf16x8 xf = {};
      if (kg < 2) {
        const float4* p = (const float4*)(x + (b * 256 + tok) * 16 + kg * 8);
        xf = pack8(p[0], p[1]);
      }
      f32x4 c0 = {0.f, 0.f, 0.f, 0.f}, c1 = {0.f, 0.f, 0.f, 0.f};
      c0 = MFMA(wa0, xf, c0, 0, 0, 0);
      c1 = MFMA(wa1, xf, c1, 0, 0, 0);
      float u0 = c0[0] + bias0.x; u0 = u0 > 0.f ? u0 : 0.f;
      float u1 = c0[1] + bias0.y; u1 = u1 > 0.f ? u1 : 0.f;
      float u2 = c0[2] + bias0.z; u2 = u2 > 0.f ? u2 : 0.f;
      float u3 = c0[3] + bias0.w; u3 = u3 > 0.f ? u3 : 0.f;
      short4 s0 = {f2bf(u0), f2bf(u1), f2bf(u2), f2bf(u3)};
      *(short4*)(h1s + tok * 264 + (2 * w) * 16 + kg * 4) = s0;
      float v0 = c1[0] + bias1.x; v0 = v0 > 0.f ? v0 : 0.f;
      float v1 = c1[1] + bias1.y; v1 = v1 > 0.f ? v1 : 0.f;
      float v2 = c1[2] + bias1.z; v2 = v2 > 0.f ? v2 : 0.f;
      float v3 = c1[3] + bias1.w; v3 = v3 > 0.f ? v3 : 0.f;
      short4 s1 = {f2bf(v0), f2bf(v1), f2bf(v2), f2bf(v3)};
      *(short4*)(h1s + tok * 264 + (2 * w + 1) * 16 + kg * 4) = s1;
    }
  }
  __syncthreads();

  // ---- GEMM2: h2 = relu(W2 x h1^T + b2); acc 2mt x 16nt, wa prefetch ----
  f32x4 acc2[2][16];
#pragma unroll
  for (int i = 0; i < 2; ++i)
#pragma unroll
    for (int j = 0; j < 16; ++j) acc2[i][j] = (f32x4){0.f, 0.f, 0.f, 0.f};

  bf16x8 wa0 = *(const bf16x8*)(W2f + ((2 * w) * 64 + lane) * 8);
  bf16x8 wa1 = *(const bf16x8*)(W2f + ((2 * w + 1) * 64 + lane) * 8);
  for (int kk = 0; kk < 8; ++kk) {
    bf16x8 nwa0, nwa1;
    if (kk < 7) {
      const short* wb = W2f + (((kk + 1) * 16 + 2 * w) * 64 + lane) * 8;
      nwa0 = *(const bf16x8*)wb;
      nwa1 = *(const bf16x8*)(wb + 512);
    }
#pragma unroll
    for (int g = 0; g < 4; ++g) {
      bf16x8 hb[4];
#pragma unroll
      for (int j = 0; j < 4; ++j)
        hb[j] = *(const bf16x8*)(h1s + ((g * 4 + j) * 16 + l15) * 264 + kk * 32 + kg * 8);
#pragma unroll
      for (int j = 0; j < 4; ++j) {
        acc2[0][g * 4 + j] = MFMA(wa0, hb[j], acc2[0][g * 4 + j], 0, 0, 0);
        acc2[1][g * 4 + j] = MFMA(wa1, hb[j], acc2[1][g * 4 + j], 0, 0, 0);
      }
    }
    wa0 = nwa0; wa1 = nwa1;
  }
  __syncthreads();   // all h1 reads done -> overlay h2

  {
    const float4 bias0 = *(const float4*)(b2g + (2 * w) * 16 + kg * 4);
    const float4 bias1 = *(const float4*)(b2g + (2 * w + 1) * 16 + kg * 4);
#pragma unroll
    for (int j = 0; j < 16; ++j) {
      const int tok = j * 16 + l15;
      float u0 = acc2[0][j][0] + bias0.x; u0 = u0 > 0.f ? u0 : 0.f;
      float u1 = acc2[0][j][1] + bias0.y; u1 = u1 > 0.f ? u1 : 0.f;
      float u2 = acc2[0][j][2] + bias0.z; u2 = u2 > 0.f ? u2 : 0.f;
      float u3 = acc2[0][j][3] + bias0.w; u3 = u3 > 0.f ? u3 : 0.f;
      short4 s0 = {f2bf(u0), f2bf(u1), f2bf(u2), f2bf(u3)};
      *(short4*)(h1s + tok * 264 + (2 * w) * 16 + kg * 4) = s0;
      float v0 = acc2[1][j][0] + bias1.x; v0 = v0 > 0.f ? v0 : 0.f;
      float v1 = acc2[1][j][1] + bias1.y; v1 = v1 > 0.f ? v1 : 0.f;
      float v2 = acc2[1][j][2] + bias1.z; v2 = v2 > 0.f ? v2 : 0.f;
      float v3 = acc2[1][j][3] + bias1.w; v3 = v3 > 0.f ? v3 : 0.f;
      short4 s1 = {f2bf(v0), f2bf(v1), f2bf(v2), f2bf(v3)};
      *(short4*)(h1s + tok * 264 + (2 * w + 1) * 16 + kg * 4) = s1;
    }
  }
  __syncthreads();

  // ---- GEMM3: g = W3 x h2^T; wave w -> mt3 = w&3, nt = (w>>2)*8 + j ----
  const int mt3 = w & 3;
  const int nh  = w >> 2;
  f32x4 acc3[8];
#pragma unroll
  for (int j = 0; j < 8; ++j) acc3[j] = (f32x4){0.f, 0.f, 0.f, 0.f};
#pragma unroll 2
  for (int kk = 0; kk < 8; ++kk) {
    const bf16x8 wa = *(const bf16x8*)(W3f + ((kk * 4 + mt3) * 64 + lane) * 8);
#pragma unroll
    for (int j = 0; j < 8; ++j) {
      const bf16x8 hb =
          *(const bf16x8*)(h1s + ((nh * 8 + j) * 16 + l15) * 264 + kk * 32 + kg * 8);
      acc3[j] = MFMA(wa, hb, acc3[j], 0, 0, 0);
    }
  }

  // y g-part: one float4 per tile
#pragma unroll
  for (int j = 0; j < 8; ++j) {
    const int tok = (nh * 8 + j) * 16 + l15;
    *(float4*)(y + (b * 256 + tok) * 80 + 16 + mt3 * 16 + kg * 4) =
        *(float4*)&acc3[j];
  }
}

// ---------------------------------------------------------------------------
// ypred (round-11 proven, standalone): block = (bc: 128 rows, one t), 256 thr.
// A hi/lo frags direct from the y0 frag table; B-frags from the K^t table.
// ---------------------------------------------------------------------------
__global__ __launch_bounds__(256, 4) void ypred_kernel(const short* __restrict__ ws,
                                                       float* __restrict__ yp) {
  const int tid  = threadIdx.x;
  const int lane = tid & 63;
  const int w    = tid >> 6;           // 0..3
  const int m16  = lane & 15;
  const int kg   = lane >> 4;
  const int bc   = blockIdx.x & 31;
  const int t    = blockIdx.x >> 5;    // 0..63
  const long b0  = (long)bc * 128;
  const short* y0f = ws + Y0F;

  if (t == 0) {
    for (int i = tid; i < 10240; i += 256) {
      const int r = i / 80, c = i - (i / 80) * 80;
      const int gmt = bc * 8 + (r >> 4);
      const int idx = ((gmt * 3 + (c >> 5)) * 64 + ((c & 31) >> 3) * 16 + (r & 15)) * 8 + (c & 7);
      yp[(b0 + r) * YROW + c] = bf2f(y0f[idx]) + bf2f(y0f[HPLANE + idx]);
    }
    return;
  }

  bf16x8 ah[2][3], al[2][3];
#pragma unroll
  for (int m = 0; m < 2; ++m) {
    const int gmt = bc * 8 + 2 * w + m;
#pragma unroll
    for (int kk = 0; kk < 3; ++kk) {
      const int idx = ((gmt * 3 + kk) * 64 + lane) * 8;
      ah[m][kk] = *(const bf16x8*)(y0f + idx);
      al[m][kk] = *(const bf16x8*)(y0f + HPLANE + idx);
    }
  }

  const short* kt = ws + KTAB + t * KSLOT;
  f32x4 acc[2][5];
#pragma unroll
  for (int m = 0; m < 2; ++m)
#pragma unroll
    for (int nt = 0; nt < 5; ++nt) acc[m][nt] = (f32x4){0.f, 0.f, 0.f, 0.f};

#pragma unroll
  for (int kk = 0; kk < 3; ++kk) {
#pragma unroll
    for (int nt = 0; nt < 5; ++nt) {
      const bf16x8 bh = *(const bf16x8*)(kt + ((kk * 5 + nt) * 64 + lane) * 8);
      const bf16x8 bl = *(const bf16x8*)(kt + 7680 + ((kk * 5 + nt) * 64 + lane) * 8);
#pragma unroll
      for (int m = 0; m < 2; ++m) {
        acc[m][nt] = MFMA(ah[m][kk], bh, acc[m][nt], 0, 0, 0);
        acc[m][nt] = MFMA(al[m][kk], bh, acc[m][nt], 0, 0, 0);
        acc[m][nt] = MFMA(ah[m][kk], bl, acc[m][nt], 0, 0, 0);
      }
    }
  }
#pragma unroll
  for (int m = 0; m < 2; ++m)
#pragma unroll
    for (int nt = 0; nt < 5; ++nt)
#pragma unroll
      for (int r = 0; r < 4; ++r)
        yp[(b0 + (2 * w + m) * 16 + kg * 4 + r) * YROW + (long)t * 80 + nt * 16 + m16] =
            acc[m][nt][r];
}

extern "C" void kernel_launch(void* const* d_in, const int* in_sizes, int n_in,
                              void* d_out, int out_size, void* d_ws, size_t ws_size,
                              hipStream_t stream) {
  const float* x  = (const float*)d_in[0];
  const float* W1 = (const float*)d_in[1];
  const float* b1 = (const float*)d_in[2];
  const float* W2 = (const float*)d_in[3];
  const float* b2 = (const float*)d_in[4];
  const float* W3 = (const float*)d_in[5];
  const float* Kg = (const float*)d_in[6];
  float* y  = (float*)d_out;
  float* yp = y + (long)NB * YROW;
  short* ws = (short*)d_ws;

  prep_kernel<<<256, 256, 0, stream>>>(W1, W2, W3, ws);
  kpow_mlp0_kernel<<<127, 256, 5 * FIMG_B, stream>>>(Kg, x, b1, b2, ws);
  mlp256_kernel<<<NB / 4, 512, 256 * 264 * 2, stream>>>(x, b1, b2, ws, y);
  ypred_kernel<<<32 * 64, 256, 0, stream>>>(ws, yp);
}

// Round 13
// 106.862 us; speedup vs baseline: 1.5925x; 1.5925x over previous
//
#include <hip/hip_runtime.h>
#include <hip/hip_bf16.h>

// Problem constants (hardcoded from setup_inputs; n_shifts == T == 64)
#define NB   4096
#define NT   64
#define NDIM 16
#define NH1  256
#define NH2  256
#define NLAT 64
#define NKD  80
#define YROW (NT * NKD)      // 5120 floats per batch row of y / y_pred
#define KTAB 98304           // short-offset of K-power fragment table in ws
#define KSLOT 15360          // shorts per t-slot (7680 hi + 7680 lo)
#define Y0F   1081344        // short-offset of y0 A-frag table
#define HPLANE 393216        // shorts per plane: 256 mtiles x 3 kk x 64 lane x 8 e

// kpow frag-image geometry: hi at [row][0..79], lo at [row][96..175]
#define FROW 184
#define FIMG_B (80 * FROW * 2)   // 29440 bytes per image

typedef __attribute__((ext_vector_type(8))) short bf16x8;
typedef __attribute__((ext_vector_type(4))) float f32x4;

#define MFMA __builtin_amdgcn_mfma_f32_16x16x32_bf16

static __device__ __forceinline__ short f2bf(float f) {
  __hip_bfloat16 b = __float2bfloat16(f);      // native RNE cast (m240)
  return __builtin_bit_cast(short, b);
}
static __device__ __forceinline__ float bf2f(short h) {
  union { unsigned u; float f; } v; v.u = ((unsigned)(unsigned short)h) << 16;
  return v.f;
}
static __device__ __forceinline__ bf16x8 pack8(float4 a, float4 b) {
  bf16x8 r;
  r[0] = f2bf(a.x); r[1] = f2bf(a.y); r[2] = f2bf(a.z); r[3] = f2bf(a.w);
  r[4] = f2bf(b.x); r[5] = f2bf(b.y); r[6] = f2bf(b.z); r[7] = f2bf(b.w);
  return r;
}

// ---------------------------------------------------------------------------
// Prep: MFMA fragment order (bf16) for 16x16x32.
// Fragment: lane l holds W[g][k] with g = l&15, k = 8*(l>>4)+e.
// ws (shorts): [0) W2f 65536 | [65536) W3f 16384 | [81920) W1f 8192
// ---------------------------------------------------------------------------
__global__ __launch_bounds__(256) void prep_kernel(const float* __restrict__ W1,
                                                   const float* __restrict__ W2,
                                                   const float* __restrict__ W3,
                                                   short* __restrict__ ws) {
  int i = blockIdx.x * 256 + threadIdx.x;   // 0..65535
  {
    int e = i & 7, l = (i >> 3) & 63, nt = (i >> 9) & 15, kk = i >> 13;
    int g = nt * 16 + (l & 15);
    int h = kk * 32 + (l >> 4) * 8 + e;
    ws[i] = f2bf(W2[g * NH1 + h]);
  }
  if (i < 16384) {
    int e = i & 7, l = (i >> 3) & 63, nt = (i >> 9) & 3, kk = i >> 11;
    int g = nt * 16 + (l & 15);
    int h = kk * 32 + (l >> 4) * 8 + e;
    ws[65536 + i] = f2bf(W3[g * NH2 + h]);
  }
  if (i < 8192) {
    int e = i & 7, l = (i >> 3) & 63, nt = i >> 9;
    int g = nt * 16 + (l & 15);
    int k = (l >> 4) * 8 + e;
    ws[81920 + i] = (k < NDIM) ? f2bf(W1[g * NDIM + k]) : (short)0;
  }
}

// ---------------------------------------------------------------------------
// MLP body (round-8 proven, 16x16x32, swapped operands, 4 waves, 64 tokens).
// MODE 0: write y rows (80 floats/token). MODE 1 (mlp0): write the y0 hi/lo
// A-fragment table at ws[Y0F] instead (plane layout [gmt][kk][lane][e]).
// tid is TEAM-LOCAL (0..255); h1s is the team's private 33792-B LDS carve.
// ---------------------------------------------------------------------------
template <int XSTRIDE, int MODE>
static __device__ __forceinline__ void mlp_body(long b, const float* __restrict__ x,
                                                const float* __restrict__ b1g,
                                                const float* __restrict__ b2g,
                                                const short* __restrict__ ws,
                                                float* __restrict__ yo,
                                                short* __restrict__ y0f,
                                                short* h1s, int tid) {
  const int lane = tid & 63;
  const int w    = tid >> 6;            // 0..3
  const int l15  = lane & 15;
  const int kg   = lane >> 4;

  const short* W2f = ws;
  const short* W3f = ws + 65536;
  const short* W1f = ws + 81920;

  const float4 xv =
      *(const float4*)(x + (b * 64 + (tid >> 2)) * XSTRIDE + (tid & 3) * 4);

  // ---- x B-frags (x^T): lane holds x[tok][k0..k0+7], tok = col ----
  bf16x8 xf[4];
#pragma unroll
  for (int j = 0; j < 4; ++j) {
    const int tok = j * 16 + l15;
    bf16x8 f = {};
    if (kg < 2) {
      const float4* p = (const float4*)(x + (b * 64 + tok) * XSTRIDE + kg * 8);
      f = pack8(p[0], p[1]);
    }
    xf[j] = f;
  }

  // ---- GEMM1: D = W1 x x^T -> h1[tok][h] via packed b64 stores ----
#pragma unroll
  for (int i = 0; i < 4; ++i) {
    const int mt = w * 4 + i;
    const bf16x8 wa = *(const bf16x8*)(W1f + (mt * 64 + lane) * 8);
    const float4 bias = *(const float4*)(b1g + mt * 16 + kg * 4);
#pragma unroll
    for (int j = 0; j < 4; ++j) {
      f32x4 c = {0.f, 0.f, 0.f, 0.f};
      c = MFMA(wa, xf[j], c, 0, 0, 0);
      const int tok = j * 16 + l15;
      float v0 = c[0] + bias.x; v0 = v0 > 0.f ? v0 : 0.f;
      float v1 = c[1] + bias.y; v1 = v1 > 0.f ? v1 : 0.f;
      float v2 = c[2] + bias.z; v2 = v2 > 0.f ? v2 : 0.f;
      float v3 = c[3] + bias.w; v3 = v3 > 0.f ? v3 : 0.f;
      short4 st = {f2bf(v0), f2bf(v1), f2bf(v2), f2bf(v3)};
      *(short4*)(h1s + tok * 264 + mt * 16 + kg * 4) = st;
    }
  }
  __syncthreads();

  // ---- GEMM2: D = W2 x h1^T; K=256; acc 4mt x 4nt ----
  f32x4 acc2[4][4];
#pragma unroll
  for (int i = 0; i < 4; ++i)
#pragma unroll
    for (int j = 0; j < 4; ++j) acc2[i][j] = (f32x4){0.f, 0.f, 0.f, 0.f};

#pragma unroll 2
  for (int kk = 0; kk < 8; ++kk) {
    bf16x8 wa[4], hb[4];
#pragma unroll
    for (int i = 0; i < 4; ++i)
      wa[i] = *(const bf16x8*)(W2f + ((kk * 16 + w * 4 + i) * 64 + lane) * 8);
#pragma unroll
    for (int j = 0; j < 4; ++j)
      hb[j] = *(const bf16x8*)(h1s + (j * 16 + l15) * 264 + kk * 32 + kg * 8);
#pragma unroll
    for (int i = 0; i < 4; ++i)
#pragma unroll
      for (int j = 0; j < 4; ++j)
        acc2[i][j] = MFMA(wa[i], hb[j], acc2[i][j], 0, 0, 0);
  }
  __syncthreads();   // all h1 reads done -> overlay h2

#pragma unroll
  for (int i = 0; i < 4; ++i) {
    const int mt = w * 4 + i;
    const float4 bias = *(const float4*)(b2g + mt * 16 + kg * 4);
#pragma unroll
    for (int j = 0; j < 4; ++j) {
      const int tok = j * 16 + l15;
      float v0 = acc2[i][j][0] + bias.x; v0 = v0 > 0.f ? v0 : 0.f;
      float v1 = acc2[i][j][1] + bias.y; v1 = v1 > 0.f ? v1 : 0.f;
      float v2 = acc2[i][j][2] + bias.z; v2 = v2 > 0.f ? v2 : 0.f;
      float v3 = acc2[i][j][3] + bias.w; v3 = v3 > 0.f ? v3 : 0.f;
      short4 st = {f2bf(v0), f2bf(v1), f2bf(v2), f2bf(v3)};
      *(short4*)(h1s + tok * 264 + mt * 16 + kg * 4) = st;
    }
  }
  __syncthreads();

  // ---- GEMM3: D = W3 x h2^T ----
  f32x4 acc3[4];
#pragma unroll
  for (int j = 0; j < 4; ++j) acc3[j] = (f32x4){0.f, 0.f, 0.f, 0.f};
#pragma unroll 2
  for (int kk = 0; kk < 8; ++kk) {
    const bf16x8 wa = *(const bf16x8*)(W3f + ((kk * 4 + w) * 64 + lane) * 8);
#pragma unroll
    for (int j = 0; j < 4; ++j) {
      const bf16x8 hb =
          *(const bf16x8*)(h1s + (j * 16 + l15) * 264 + kk * 32 + kg * 8);
      acc3[j] = MFMA(wa, hb, acc3[j], 0, 0, 0);
    }
  }

  if (MODE == 0) {
    // y x-part (exact f32 from regs) + g-part (one float4 per tile)
    *(float4*)(yo + (b * 64 + (tid >> 2)) * 80 + (tid & 3) * 4) = xv;
#pragma unroll
    for (int j = 0; j < 4; ++j) {
      const int tok = j * 16 + l15;
      *(float4*)(yo + (b * 64 + tok) * 80 + 16 + w * 16 + kg * 4) =
          *(float4*)&acc3[j];
    }
  } else {
    // ---- y0 hi/lo A-frag table epilogue ----
    {
      const int t0 = tid >> 2;
      const int gmt = (int)b * 4 + (t0 >> 4);
      const int c0x = (tid & 3) * 4;
      const int lanef = (c0x >> 3) * 16 + (t0 & 15);
      short h0 = f2bf(xv.x), h1 = f2bf(xv.y), h2 = f2bf(xv.z), h3 = f2bf(xv.w);
      short4 hs = {h0, h1, h2, h3};
      short4 ls = {f2bf(xv.x - bf2f(h0)), f2bf(xv.y - bf2f(h1)),
                   f2bf(xv.z - bf2f(h2)), f2bf(xv.w - bf2f(h3))};
      const int idx = ((gmt * 3 + 0) * 64 + lanef) * 8 + (c0x & 7);
      *(short4*)(y0f + idx) = hs;
      *(short4*)(y0f + HPLANE + idx) = ls;
    }
    const int c0 = 16 + w * 16 + kg * 4;
    const int kkf = c0 >> 5;
    const int lanef = ((c0 & 31) >> 3) * 16 + l15;
#pragma unroll
    for (int j = 0; j < 4; ++j) {
      const int gmt = (int)b * 4 + j;
      short h0 = f2bf(acc3[j][0]), h1 = f2bf(acc3[j][1]);
      short h2 = f2bf(acc3[j][2]), h3 = f2bf(acc3[j][3]);
      short4 hs = {h0, h1, h2, h3};
      short4 ls = {f2bf(acc3[j][0] - bf2f(h0)), f2bf(acc3[j][1] - bf2f(h1)),
                   f2bf(acc3[j][2] - bf2f(h2)), f2bf(acc3[j][3] - bf2f(h3))};
      const int idx = ((gmt * 3 + kkf) * 64 + lanef) * 8 + (c0 & 7);
      *(short4*)(y0f + idx) = hs;
      *(short4*)(y0f + HPLANE + idx) = ls;
    }
    // zero-fill k in [80,96): kk=2, lanes 32..63 (ws is poisoned, not zeroed)
    {
      const int plane = tid & 1;
      const int lz = 32 + ((tid >> 1) & 31);
      const int gmt = (int)b * 4 + (tid >> 6);
      bf16x8 z = {};
      *(bf16x8*)(y0f + plane * HPLANE + ((gmt * 3 + 2) * 64 + lz) * 8) = z;
    }
  }
}

// ---------------------------------------------------------------------------
// kpow+mlp0 fused launch (79 blocks x 1024 threads, 147200 B LDS):
//   bid 0..62 -> kpow: K^(bid+1), 16 waves (mm tiles id += 16 -> ~2x shorter
//               serial chain per mm than the 256-thr version).
//   bid 63..78 -> mlp0 x4: four independent 256-thr teams per block, each
//               running the token-0 MLP for 64 batch rows with a private
//               33792-B h1s carve. All teams hit the same barrier sequence.
// Both paths now run 4 waves/SIMD instead of 1 (the round-11 launch was
// occupancy-starved at 1 block/CU x 4 waves).
// ---------------------------------------------------------------------------
__global__ __launch_bounds__(1024, 4) void kpow_mlp0_kernel(const float* __restrict__ Kg,
                                                            const float* __restrict__ x,
                                                            const float* __restrict__ b1g,
                                                            const float* __restrict__ b2g,
                                                            short* __restrict__ ws) {
  extern __shared__ char smem[];
  const int tid = threadIdx.x;

  if (blockIdx.x >= 63) {
    const int team = tid >> 8;           // 0..3
    const int ttid = tid & 255;
    const long b = (long)(blockIdx.x - 63) * 4 + team;   // 0..63
    mlp_body<1024, 1>(b, x, b1g, b2g, ws, nullptr, ws + Y0F,
                      (short*)(smem + team * 33792), ttid);
    return;
  }

  short* kA   = (short*)smem;
  short* curA = (short*)(smem + FIMG_B);
  short* curB = (short*)(smem + 2 * FIMG_B);
  short* nxtA = (short*)(smem + 3 * FIMG_B);
  short* nxtB = (short*)(smem + 4 * FIMG_B);

  const int lane = tid & 63;
  const int w    = tid >> 6;            // 0..15
  const int l15  = lane & 15;
  const int kg   = lane >> 4;
  const int t    = blockIdx.x + 1;      // 1..63

  for (int i = tid; i < 6400; i += 1024) {
    float v = Kg[i];
    int r = i / 80, c = i - r * 80;
    short hi = f2bf(v);
    short lo = f2bf(v - bf2f(hi));
    kA[r * FROW + c] = hi;        kA[r * FROW + 96 + c] = lo;
    curA[r * FROW + c] = hi;      curA[r * FROW + 96 + c] = lo;
    curB[c * FROW + r] = hi;      curB[c * FROW + 96 + r] = lo;
  }
  __syncthreads();

  auto mm = [&](const short* Ai, const short* Bi, short* DA, short* DB) {
    for (int id = w; id < 25; id += 16) {
      const int mt = id / 5, nt = id % 5;
      f32x4 acc = {0.f, 0.f, 0.f, 0.f};
#pragma unroll
      for (int kk = 0; kk < 3; ++kk) {
        const int k0 = kk * 32 + kg * 8;
        bf16x8 ah = {}, al = {}, bh = {}, bl = {};
        if (k0 < 80) {
          const short* ap = Ai + (mt * 16 + l15) * FROW + k0;
          const short* bp = Bi + (nt * 16 + l15) * FROW + k0;
          ah = *(const bf16x8*)ap;  al = *(const bf16x8*)(ap + 96);
          bh = *(const bf16x8*)bp;  bl = *(const bf16x8*)(bp + 96);
        }
        acc = MFMA(ah, bh, acc, 0, 0, 0);
        acc = MFMA(al, bh, acc, 0, 0, 0);
        acc = MFMA(ah, bl, acc, 0, 0, 0);
      }
      const int n = nt * 16 + l15;
      const int rowb = mt * 16 + kg * 4;
      short4 hs, ls;
#pragma unroll
      for (int r = 0; r < 4; ++r) {
        float v = acc[r];
        short hi = f2bf(v);
        short lo = f2bf(v - bf2f(hi));
        DA[(rowb + r) * FROW + n] = hi;
        DA[(rowb + r) * FROW + 96 + n] = lo;
        ((short*)&hs)[r] = hi;
        ((short*)&ls)[r] = lo;
      }
      *(short4*)(DB + n * FROW + rowb) = hs;
      *(short4*)(DB + n * FROW + 96 + rowb) = ls;
    }
    __syncthreads();
  };

  const int h = 31 - __clz(t);
  for (int bit = h - 1; bit >= 0; --bit) {
    mm(curA, curB, nxtA, nxtB);                               // square
    { short* p;
      p = curA; curA = nxtA; nxtA = p;
      p = curB; curB = nxtB; nxtB = p; }
    if ((t >> bit) & 1) {
      mm(kA, curB, nxtA, nxtB);                               // K * cur
      { short* p;
        p = curA; curA = nxtA; nxtA = p;
        p = curB; curB = nxtB; nxtB = p; }
    }
  }

  short* kt = ws + KTAB + t * KSLOT;
  for (int s = tid; s < 960; s += 1024) {
    int f = s >> 6, ln = s & 63;            // f = kk*5 + nt
    int kk = f / 5, nt = f % 5;
    int k0 = kk * 32 + (ln >> 4) * 8;
    int n  = nt * 16 + (ln & 15);
    bf16x8 h8 = {}, l8 = {};
    if (k0 < 80) {
      const short* ap = curA + n * FROW + k0;
      h8 = *(const bf16x8*)ap;
      l8 = *(const bf16x8*)(ap + 96);
    }
    *(bf16x8*)(kt + f * 512 + ln * 8) = h8;
    *(bf16x8*)(kt + 7680 + f * 512 + ln * 8) = l8;
  }
}

// ---------------------------------------------------------------------------
// ypred body (256 thr): block = (bc: 128 batch rows, one t). Wave w owns
// local M-tiles {2w, 2w+1}. A hi/lo frags load DIRECTLY from the y0 frag
// table; B-frags from the K^t table. t=0 blocks reconstruct y0 = hi + lo.
// ---------------------------------------------------------------------------
static __device__ __forceinline__ void ypred_body(int g, const short* __restrict__ ws,
                                                  float* __restrict__ yp, int tid) {
  const int lane = tid & 63;
  const int w    = tid >> 6;           // 0..3
  const int m16  = lane & 15;
  const int kg   = lane >> 4;
  const int bc   = g & 31;
  const int t    = g >> 5;             // 0..63
  const long b0  = (long)bc * 128;
  const short* y0f = ws + Y0F;

  if (t == 0) {
    for (int i = tid; i < 10240; i += 256) {
      const int r = i / 80, c = i - (i / 80) * 80;
      const int gmt = bc * 8 + (r >> 4);
      const int idx = ((gmt * 3 + (c >> 5)) * 64 + ((c & 31) >> 3) * 16 + (r & 15)) * 8 + (c & 7);
      yp[(b0 + r) * YROW + c] = bf2f(y0f[idx]) + bf2f(y0f[HPLANE + idx]);
    }
    return;
  }

  bf16x8 ah[2][3], al[2][3];
#pragma unroll
  for (int m = 0; m < 2; ++m) {
    const int gmt = bc * 8 + 2 * w + m;
#pragma unroll
    for (int kk = 0; kk < 3; ++kk) {
      const int idx = ((gmt * 3 + kk) * 64 + lane) * 8;
      ah[m][kk] = *(const bf16x8*)(y0f + idx);
      al[m][kk] = *(const bf16x8*)(y0f + HPLANE + idx);
    }
  }

  const short* kt = ws + KTAB + t * KSLOT;
  f32x4 acc[2][5];
#pragma unroll
  for (int m = 0; m < 2; ++m)
#pragma unroll
    for (int nt = 0; nt < 5; ++nt) acc[m][nt] = (f32x4){0.f, 0.f, 0.f, 0.f};

#pragma unroll
  for (int kk = 0; kk < 3; ++kk) {
#pragma unroll
    for (int nt = 0; nt < 5; ++nt) {
      const bf16x8 bh = *(const bf16x8*)(kt + ((kk * 5 + nt) * 64 + lane) * 8);
      const bf16x8 bl = *(const bf16x8*)(kt + 7680 + ((kk * 5 + nt) * 64 + lane) * 8);
#pragma unroll
      for (int m = 0; m < 2; ++m) {
        acc[m][nt] = MFMA(ah[m][kk], bh, acc[m][nt], 0, 0, 0);
        acc[m][nt] = MFMA(al[m][kk], bh, acc[m][nt], 0, 0, 0);
        acc[m][nt] = MFMA(ah[m][kk], bl, acc[m][nt], 0, 0, 0);
      }
    }
  }
#pragma unroll
  for (int m = 0; m < 2; ++m)
#pragma unroll
    for (int nt = 0; nt < 5; ++nt)
#pragma unroll
      for (int r = 0; r < 4; ++r)
        yp[(b0 + (2 * w + m) * 16 + kg * 4 + r) * YROW + (long)t * 80 + nt * 16 + m16] =
            acc[m][nt][r];
}

// ---------------------------------------------------------------------------
// Fused kernel (round-11 proven, unchanged): 6144 blocks. bid%3==2 -> ypred
// block (write-BW bound), else -> mlp block (latency bound); interleave
// co-resides them per CU so ypred's HBM writes hide under mlp's stalls.
// ---------------------------------------------------------------------------
__global__ __launch_bounds__(256, 4) void fused_kernel(const float* __restrict__ x,
                                                       const float* __restrict__ b1g,
                                                       const float* __restrict__ b2g,
                                                       const short* __restrict__ ws,
                                                       float* __restrict__ y,
                                                       float* __restrict__ yp) {
  extern __shared__ char smem[];
  const int bid = blockIdx.x;
  const int g = bid / 3;
  const int r = bid - 3 * g;
  if (r == 2) {
    ypred_body(g, ws, yp, threadIdx.x);
  } else {
    mlp_body<16, 0>((long)(g * 2 + r), x, b1g, b2g, ws, y, nullptr,
                    (short*)smem, threadIdx.x);
  }
}

extern "C" void kernel_launch(void* const* d_in, const int* in_sizes, int n_in,
                              void* d_out, int out_size, void* d_ws, size_t ws_size,
                              hipStream_t stream) {
  const float* x  = (const float*)d_in[0];
  const float* W1 = (const float*)d_in[1];
  const float* b1 = (const float*)d_in[2];
  const float* W2 = (const float*)d_in[3];
  const float* b2 = (const float*)d_in[4];
  const float* W3 = (const float*)d_in[5];
  const float* Kg = (const float*)d_in[6];
  float* y  = (float*)d_out;
  float* yp = y + (long)NB * YROW;
  short* ws = (short*)d_ws;

  prep_kernel<<<256, 256, 0, stream>>>(W1, W2, W3, ws);
  kpow_mlp0_kernel<<<79, 1024, 5 * FIMG_B, stream>>>(Kg, x, b1, b2, ws);
  fused_kernel<<<6144, 256, 64 * 264 * 2, stream>>>(x, b1, b2, ws, y, yp);
}